// Round 10
// baseline (49.185 us; speedup 1.0000x reference)
//
#include <hip/hip_runtime.h>
#include <math.h>

#define B_  2048
#define T_  200
#define D_  64
#define H1_ 80
#define H2_ 40

#define WSTR 104   // ws W2T row stride (bf16)
#define HSTR 104   // h1 row stride (bf16); cols 80..95 zero pad

// d_ws layout (bytes):
#define WS_A    0        // A[h][f]  bf16 [80][64]
#define WS_C    10240    // C[h][f]  bf16 [80][64]
#define WS_W2T  20480    // W2Tp[g][h] bf16 [48][104]
#define WS_ACT  30464    // W1acT[h][f] f32 [80][64]

typedef __bf16 bf16x8 __attribute__((ext_vector_type(8)));
typedef float  f32x4  __attribute__((ext_vector_type(4)));

__device__ __forceinline__ float sigmoidf_(float x) {
    return __builtin_amdgcn_rcpf(1.0f + __expf(-x));
}

// ---------- prep: block-invariant weight transforms ----------
__global__ __launch_bounds__(256)
void prep_kernel(const float* __restrict__ W1, const float* __restrict__ W2,
                 void* __restrict__ ws)
{
    __bf16* A    = (__bf16*)((char*)ws + WS_A);
    __bf16* C    = (__bf16*)((char*)ws + WS_C);
    __bf16* W2Tp = (__bf16*)((char*)ws + WS_W2T);
    float*  acT  = (float*)((char*)ws + WS_ACT);
    const int e0 = blockIdx.x * 256 + threadIdx.x;

    for (int e = e0; e < H1_ * D_; e += 2048) {
        int h = e >> 6, f = e & 63;
        float wb = W1[(64  + f) * H1_ + h];
        float wc = W1[(128 + f) * H1_ + h];
        float wd = W1[(192 + f) * H1_ + h];
        float wa = W1[f * H1_ + h];
        A[e]   = (__bf16)(wb - wc);
        C[e]   = (__bf16)wd;
        acT[e] = wa + wc;
    }
    for (int e = e0; e < 48 * WSTR; e += 2048) {
        int g = e / WSTR, h = e - g * WSTR;
        W2Tp[e] = (g < H2_ && h < H1_) ? (__bf16)W2[h * H2_ + g] : (__bf16)0.0f;
    }
}

// ---------- main: one batch per wave, flash accumulation, zero barriers ----------
__global__ __launch_bounds__(256, 2)
void attn_din10(const float* __restrict__ query,
                const float* __restrict__ key,
                const int*   __restrict__ mask,
                const float* __restrict__ b1,
                const float* __restrict__ b2,
                const float* __restrict__ W3,
                const float* __restrict__ b3,
                const void*  __restrict__ ws,
                float* __restrict__ out)
{
    __shared__ __align__(16) __bf16 s_h1[4][16 * HSTR];    // 13312 B (per-wave)
    __shared__ __align__(16) float  s_q[4][D_];            //  1024 B
    __shared__ float s_base[4][H1_];                        //  1280 B
    __shared__ float s_sc16[4][16];                         //   256 B
    __shared__ float s_part[4][D_];                         //  1024 B
    // ~16.9 KB total

    const int tid  = threadIdx.x;
    const int lane = tid & 63;
    const int w    = tid >> 6;
    const int c16  = lane & 15;
    const int g16  = lane >> 4;
    const int b    = blockIdx.x * 4 + w;       // wave-private batch

    const int   mv     = mask[b];
    const int   ntiles = (mv + 15) >> 4;
    const float b3v    = b3[0];
    const float* kb = key + (size_t)b * T_ * D_;

    const __bf16* wsA   = (const __bf16*)((const char*)ws + WS_A);
    const __bf16* wsC   = (const __bf16*)((const char*)ws + WS_C);
    const __bf16* wsW2T = (const __bf16*)((const char*)ws + WS_W2T);
    const float*  wsacT = (const float*) ((const char*)ws + WS_ACT);

    // ---- issue q + tile-0 key loads early ----
    float qv = query[b * D_ + lane];
    float4 u0, u1, u2, u3;
    {
        const float* kr = kb + (size_t)c16 * D_ + g16 * 8;  // tile 0 always live (mv>=1)
        u0 = *(const float4*)(kr);
        u1 = *(const float4*)(kr + 4);
        u2 = *(const float4*)(kr + 32);
        u3 = *(const float4*)(kr + 36);
    }
    s_q[w][lane] = qv;

    // ---- W2T fragments into registers (L2-resident ws) ----
    bf16x8 bw[3][3];
    #pragma unroll
    for (int nt = 0; nt < 3; ++nt)
        #pragma unroll
        for (int ks = 0; ks < 3; ++ks)
            bw[nt][ks] = *(const bf16x8*)&wsW2T[(nt * 16 + c16) * WSTR + ks * 32 + g16 * 8];

    float b2c[3], w3c[3];
    #pragma unroll
    for (int nt = 0; nt < 3; ++nt) {
        int g = nt * 16 + c16;
        b2c[nt] = (g < H2_) ? b2[g] : 0.0f;
        w3c[nt] = (g < H2_) ? W3[g] : 0.0f;
    }

    // ---- base[h] = b1[h] + q.(W1a+W1c) ----
    {
        float a0 = b1[lane], a1 = 0.0f, a2 = 0.0f, a3 = 0.0f;
        const f32x4* row = (const f32x4*)&wsacT[lane * D_];
        #pragma unroll
        for (int f4 = 0; f4 < 16; ++f4) {
            f32x4 v  = row[f4];
            f32x4 q4 = *(const f32x4*)&s_q[w][f4 * 4];
            a0 = fmaf(q4[0], v[0], a0);
            a1 = fmaf(q4[1], v[1], a1);
            a2 = fmaf(q4[2], v[2], a2);
            a3 = fmaf(q4[3], v[3], a3);
        }
        s_base[w][lane] = (a0 + a1) + (a2 + a3);
    }
    if (lane < 16) {
        int h = 64 + lane;
        float a0 = b1[h], a1 = 0.0f, a2 = 0.0f, a3 = 0.0f;
        const f32x4* row = (const f32x4*)&wsacT[h * D_];
        #pragma unroll
        for (int f4 = 0; f4 < 16; ++f4) {
            f32x4 v  = row[f4];
            f32x4 q4 = *(const f32x4*)&s_q[w][f4 * 4];
            a0 = fmaf(q4[0], v[0], a0);
            a1 = fmaf(q4[1], v[1], a1);
            a2 = fmaf(q4[2], v[2], a2);
            a3 = fmaf(q4[3], v[3], a3);
        }
        s_base[w][h] = (a0 + a1) + (a2 + a3);
    }

    // ---- V B-fragments in registers: bv[nt][ks][j] = A + q*C at (h=nt*16+c16, f=ks*32+g16*8+j) ----
    bf16x8 bv[5][2];
    #pragma unroll
    for (int nt = 0; nt < 5; ++nt)
        #pragma unroll
        for (int ks = 0; ks < 2; ++ks) {
            int off = (nt * 16 + c16) * D_ + ks * 32 + g16 * 8;
            bf16x8 a8 = *(const bf16x8*)&wsA[off];
            bf16x8 c8 = *(const bf16x8*)&wsC[off];
            f32x4 q0 = *(const f32x4*)&s_q[w][ks * 32 + g16 * 8];
            f32x4 q1 = *(const f32x4*)&s_q[w][ks * 32 + g16 * 8 + 4];
            bf16x8 v8;
            v8[0] = (__bf16)((float)a8[0] + q0[0] * (float)c8[0]);
            v8[1] = (__bf16)((float)a8[1] + q0[1] * (float)c8[1]);
            v8[2] = (__bf16)((float)a8[2] + q0[2] * (float)c8[2]);
            v8[3] = (__bf16)((float)a8[3] + q0[3] * (float)c8[3]);
            v8[4] = (__bf16)((float)a8[4] + q1[0] * (float)c8[4]);
            v8[5] = (__bf16)((float)a8[5] + q1[1] * (float)c8[5]);
            v8[6] = (__bf16)((float)a8[6] + q1[2] * (float)c8[6]);
            v8[7] = (__bf16)((float)a8[7] + q1[3] * (float)c8[7]);
            bv[nt][ks] = v8;
        }

    // ---- zero h1 pad cols 80..95 (wave-private, once) ----
    {
        int row = lane & 15, c0 = 80 + (lane >> 4) * 4;
        *(uint2*)&s_h1[w][row * HSTR + c0] = make_uint2(0u, 0u);
    }

    float base_c[5];
    #pragma unroll
    for (int nt = 0; nt < 5; ++nt) base_c[nt] = s_base[w][nt * 16 + c16];
    __bf16* myh = &s_h1[w][0];

    // ---- flash state ----
    float o00,o01,o02,o03,o04,o05,o06,o07,o08,o09,o10,o11,o12,o13,o14,o15;
    o00=o01=o02=o03=o04=o05=o06=o07=o08=o09=o10=o11=o12=o13=o14=o15=0.0f;
    float m_run = -1e30f, l_run = 0.0f;

    // ---------------- main loop ----------------
    for (int tt = 0; tt < ntiles; ++tt) {
        bf16x8 af0, af1;
        af0[0] = (__bf16)u0.x; af0[1] = (__bf16)u0.y; af0[2] = (__bf16)u0.z; af0[3] = (__bf16)u0.w;
        af0[4] = (__bf16)u1.x; af0[5] = (__bf16)u1.y; af0[6] = (__bf16)u1.z; af0[7] = (__bf16)u1.w;
        af1[0] = (__bf16)u2.x; af1[1] = (__bf16)u2.y; af1[2] = (__bf16)u2.z; af1[3] = (__bf16)u2.w;
        af1[4] = (__bf16)u3.x; af1[5] = (__bf16)u3.y; af1[6] = (__bf16)u3.z; af1[7] = (__bf16)u3.w;

        // T14 prefetch next tile into n (u stays live for the flash o-update)
        float4 n0 = u0, n1 = u1, n2 = u2, n3 = u3;
        if (tt + 1 < ntiles) {
            int tr = (tt + 1) * 16 + c16;
            const float* kr = kb + (size_t)((tr < T_) ? tr : (T_ - 1)) * D_ + g16 * 8;
            n0 = *(const float4*)(kr);
            n1 = *(const float4*)(kr + 4);
            n2 = *(const float4*)(kr + 32);
            n3 = *(const float4*)(kr + 36);
        }

        // layer 1 -> sigmoid -> h1 (wave-private LDS transpose); B from registers
        #pragma unroll
        for (int nt = 0; nt < 5; ++nt) {
            float bb = base_c[nt];
            f32x4 c = { bb, bb, bb, bb };
            c = __builtin_amdgcn_mfma_f32_16x16x32_bf16(af0, bv[nt][0], c, 0, 0, 0);
            c = __builtin_amdgcn_mfma_f32_16x16x32_bf16(af1, bv[nt][1], c, 0, 0, 0);
            #pragma unroll
            for (int r = 0; r < 4; ++r)
                myh[(g16 * 4 + r) * HSTR + nt * 16 + c16] = (__bf16)sigmoidf_(c[r]);
        }

        // layer 2
        bf16x8 a2_0 = *(const bf16x8*)&myh[c16 * HSTR + g16 * 8];
        bf16x8 a2_1 = *(const bf16x8*)&myh[c16 * HSTR + 32 + g16 * 8];
        bf16x8 a2_2 = *(const bf16x8*)&myh[c16 * HSTR + 64 + g16 * 8];
        f32x4 acc2[3];
        #pragma unroll
        for (int nt = 0; nt < 3; ++nt) {
            float bb = b2c[nt];
            f32x4 c = { bb, bb, bb, bb };
            c = __builtin_amdgcn_mfma_f32_16x16x32_bf16(a2_0, bw[nt][0], c, 0, 0, 0);
            c = __builtin_amdgcn_mfma_f32_16x16x32_bf16(a2_1, bw[nt][1], c, 0, 0, 0);
            c = __builtin_amdgcn_mfma_f32_16x16x32_bf16(a2_2, bw[nt][2], c, 0, 0, 0);
            acc2[nt] = c;
        }

        // layer 3 + masked score -> s_sc16 (all 16 slots written)
        const int tb = tt * 16;
        #pragma unroll
        for (int r = 0; r < 4; ++r) {
            float partial = sigmoidf_(acc2[0][r]) * w3c[0]
                          + sigmoidf_(acc2[1][r]) * w3c[1]
                          + sigmoidf_(acc2[2][r]) * w3c[2];
            partial += __shfl_xor(partial, 1);
            partial += __shfl_xor(partial, 2);
            partial += __shfl_xor(partial, 4);
            partial += __shfl_xor(partial, 8);
            if (c16 == 0) {
                int t = tb + g16 * 4 + r;
                s_sc16[w][g16 * 4 + r] = (t < mv) ? (partial + b3v) * 0.125f : -1e30f;
            }
        }

        // online softmax update (lane's row t = tb + c16; key of that row in u)
        float s = s_sc16[w][c16];
        float tm = s;
        tm = fmaxf(tm, __shfl_xor(tm, 1));
        tm = fmaxf(tm, __shfl_xor(tm, 2));
        tm = fmaxf(tm, __shfl_xor(tm, 4));
        tm = fmaxf(tm, __shfl_xor(tm, 8));
        float m_new = fmaxf(m_run, tm);
        float alpha = __expf(m_run - m_new);
        float p = __expf(s - m_new);
        float psum = p;
        psum += __shfl_xor(psum, 1);
        psum += __shfl_xor(psum, 2);
        psum += __shfl_xor(psum, 4);
        psum += __shfl_xor(psum, 8);
        l_run = l_run * alpha + psum;
        o00 = o00 * alpha + p * u0.x;  o01 = o01 * alpha + p * u0.y;
        o02 = o02 * alpha + p * u0.z;  o03 = o03 * alpha + p * u0.w;
        o04 = o04 * alpha + p * u1.x;  o05 = o05 * alpha + p * u1.y;
        o06 = o06 * alpha + p * u1.z;  o07 = o07 * alpha + p * u1.w;
        o08 = o08 * alpha + p * u2.x;  o09 = o09 * alpha + p * u2.y;
        o10 = o10 * alpha + p * u2.z;  o11 = o11 * alpha + p * u2.w;
        o12 = o12 * alpha + p * u3.x;  o13 = o13 * alpha + p * u3.y;
        o14 = o14 * alpha + p * u3.z;  o15 = o15 * alpha + p * u3.w;
        m_run = m_new;

        u0 = n0; u1 = n1; u2 = n2; u3 = n3;
    }

    // ---------------- finalize: reduce o over c16 lanes, normalize, store ----------------
    #define ORED(X) X += __shfl_xor(X,1); X += __shfl_xor(X,2); X += __shfl_xor(X,4); X += __shfl_xor(X,8);
    ORED(o00) ORED(o01) ORED(o02) ORED(o03) ORED(o04) ORED(o05) ORED(o06) ORED(o07)
    ORED(o08) ORED(o09) ORED(o10) ORED(o11) ORED(o12) ORED(o13) ORED(o14) ORED(o15)
    #undef ORED
    float inv_total = __builtin_amdgcn_rcpf(l_run);
    if (c16 == 0) {
        float* sp = &s_part[w][0];
        sp[g16 * 8 + 0] = o00;  sp[g16 * 8 + 1] = o01;
        sp[g16 * 8 + 2] = o02;  sp[g16 * 8 + 3] = o03;
        sp[g16 * 8 + 4] = o04;  sp[g16 * 8 + 5] = o05;
        sp[g16 * 8 + 6] = o06;  sp[g16 * 8 + 7] = o07;
        sp[32 + g16 * 8 + 0] = o08;  sp[32 + g16 * 8 + 1] = o09;
        sp[32 + g16 * 8 + 2] = o10;  sp[32 + g16 * 8 + 3] = o11;
        sp[32 + g16 * 8 + 4] = o12;  sp[32 + g16 * 8 + 5] = o13;
        sp[32 + g16 * 8 + 6] = o14;  sp[32 + g16 * 8 + 7] = o15;
    }
    asm volatile("s_waitcnt lgkmcnt(0)" ::: "memory");
    out[b * D_ + lane] = s_part[w][lane] * inv_total;
}

extern "C" void kernel_launch(void* const* d_in, const int* in_sizes, int n_in,
                              void* d_out, int out_size, void* d_ws, size_t ws_size,
                              hipStream_t stream)
{
    const float* query = (const float*)d_in[0];
    const float* key   = (const float*)d_in[1];
    const int*   mask  = (const int*)  d_in[2];
    const float* W1    = (const float*)d_in[3];
    const float* b1    = (const float*)d_in[4];
    const float* W2    = (const float*)d_in[5];
    const float* b2    = (const float*)d_in[6];
    const float* W3    = (const float*)d_in[7];
    const float* b3    = (const float*)d_in[8];
    float* out = (float*)d_out;

    prep_kernel<<<8, 256, 0, stream>>>(W1, W2, d_ws);
    attn_din10<<<512, 256, 0, stream>>>(query, key, mask, b1, b2, W3, b3, d_ws, out);
}

// Round 11
// 46.786 us; speedup vs baseline: 1.0513x; 1.0513x over previous
//
#include <hip/hip_runtime.h>
#include <math.h>

#define B_  2048
#define T_  200
#define D_  64
#define H1_ 80
#define H2_ 40

#define WSTR 104   // ws W2T row stride (bf16)
#define HSTR 104   // h1 row stride (bf16); cols 80..95 zero pad; 32 rows/wave

// d_ws layout (bytes):
#define WS_A    0        // A[h][f]  bf16 [80][64]
#define WS_C    10240    // C[h][f]  bf16 [80][64]
#define WS_W2T  20480    // W2Tp[g][h] bf16 [48][104]
#define WS_ACT  30464    // W1acT[h][f] f32 [80][64]

typedef __bf16 bf16x8 __attribute__((ext_vector_type(8)));
typedef float  f32x4  __attribute__((ext_vector_type(4)));

__device__ __forceinline__ float sigmoidf_(float x) {
    return __builtin_amdgcn_rcpf(1.0f + __expf(-x));
}

// ---------- prep: block-invariant weight transforms ----------
__global__ __launch_bounds__(256)
void prep_kernel(const float* __restrict__ W1, const float* __restrict__ W2,
                 void* __restrict__ ws)
{
    __bf16* A    = (__bf16*)((char*)ws + WS_A);
    __bf16* C    = (__bf16*)((char*)ws + WS_C);
    __bf16* W2Tp = (__bf16*)((char*)ws + WS_W2T);
    float*  acT  = (float*)((char*)ws + WS_ACT);
    const int e0 = blockIdx.x * 256 + threadIdx.x;

    for (int e = e0; e < H1_ * D_; e += 2048) {
        int h = e >> 6, f = e & 63;
        float wb = W1[(64  + f) * H1_ + h];
        float wc = W1[(128 + f) * H1_ + h];
        float wd = W1[(192 + f) * H1_ + h];
        float wa = W1[f * H1_ + h];
        A[e]   = (__bf16)(wb - wc);
        C[e]   = (__bf16)wd;
        acT[e] = wa + wc;
    }
    for (int e = e0; e < 48 * WSTR; e += 2048) {
        int g = e / WSTR, h = e - g * WSTR;
        W2Tp[e] = (g < H2_ && h < H1_) ? (__bf16)W2[h * H2_ + g] : (__bf16)0.0f;
    }
}

// ---------- main: one batch per wave, 32-row tile-pairs, flash, zero barriers ----------
__global__ __launch_bounds__(256, 2)
void attn_din11(const float* __restrict__ query,
                const float* __restrict__ key,
                const int*   __restrict__ mask,
                const float* __restrict__ b1,
                const float* __restrict__ b2,
                const float* __restrict__ W3,
                const float* __restrict__ b3,
                const void*  __restrict__ ws,
                float* __restrict__ out)
{
    __shared__ __align__(16) __bf16 s_h1[4][32 * HSTR];    // 26624 B (32 rows/wave)
    __shared__ __align__(16) float  s_q[4][D_];
    __shared__ float s_base[4][H1_];
    __shared__ float s_sc[4][32];
    __shared__ float s_part[4][D_];
    // ~31 KB total

    const int tid  = threadIdx.x;
    const int lane = tid & 63;
    const int w    = tid >> 6;
    const int c16  = lane & 15;
    const int g16  = lane >> 4;
    const int b    = blockIdx.x * 4 + w;

    const int   mv     = mask[b];
    const int   npairs = (mv + 31) >> 5;       // ceil(mv/32)
    const float b3v    = b3[0];
    const float* kb = key + (size_t)b * T_ * D_;

    const __bf16* wsA   = (const __bf16*)((const char*)ws + WS_A);
    const __bf16* wsC   = (const __bf16*)((const char*)ws + WS_C);
    const __bf16* wsW2T = (const __bf16*)((const char*)ws + WS_W2T);
    const float*  wsacT = (const float*) ((const char*)ws + WS_ACT);

    // ---- q + pair-0 key loads issued early ----
    float qv = query[b * D_ + lane];
    float4 uA0, uA1, uA2, uA3, uB0, uB1, uB2, uB3;
    {
        const float* krA = kb + (size_t)c16 * D_ + g16 * 8;          // rows 0..15
        const float* krB = kb + (size_t)(16 + c16) * D_ + g16 * 8;   // rows 16..31 (<200, valid)
        uA0 = *(const float4*)(krA);      uA1 = *(const float4*)(krA + 4);
        uA2 = *(const float4*)(krA + 32); uA3 = *(const float4*)(krA + 36);
        uB0 = *(const float4*)(krB);      uB1 = *(const float4*)(krB + 4);
        uB2 = *(const float4*)(krB + 32); uB3 = *(const float4*)(krB + 36);
    }
    s_q[w][lane] = qv;

    // ---- W2T fragments into registers ----
    bf16x8 bw[3][3];
    #pragma unroll
    for (int nt = 0; nt < 3; ++nt)
        #pragma unroll
        for (int ks = 0; ks < 3; ++ks)
            bw[nt][ks] = *(const bf16x8*)&wsW2T[(nt * 16 + c16) * WSTR + ks * 32 + g16 * 8];

    float b2c[3], w3c[3];
    #pragma unroll
    for (int nt = 0; nt < 3; ++nt) {
        int g = nt * 16 + c16;
        b2c[nt] = (g < H2_) ? b2[g] : 0.0f;
        w3c[nt] = (g < H2_) ? W3[g] : 0.0f;
    }

    // ---- base[h] ----
    {
        float a0 = b1[lane], a1 = 0.0f, a2 = 0.0f, a3 = 0.0f;
        const f32x4* row = (const f32x4*)&wsacT[lane * D_];
        #pragma unroll
        for (int f4 = 0; f4 < 16; ++f4) {
            f32x4 v  = row[f4];
            f32x4 q4 = *(const f32x4*)&s_q[w][f4 * 4];
            a0 = fmaf(q4[0], v[0], a0);
            a1 = fmaf(q4[1], v[1], a1);
            a2 = fmaf(q4[2], v[2], a2);
            a3 = fmaf(q4[3], v[3], a3);
        }
        s_base[w][lane] = (a0 + a1) + (a2 + a3);
    }
    if (lane < 16) {
        int h = 64 + lane;
        float a0 = b1[h], a1 = 0.0f, a2 = 0.0f, a3 = 0.0f;
        const f32x4* row = (const f32x4*)&wsacT[h * D_];
        #pragma unroll
        for (int f4 = 0; f4 < 16; ++f4) {
            f32x4 v  = row[f4];
            f32x4 q4 = *(const f32x4*)&s_q[w][f4 * 4];
            a0 = fmaf(q4[0], v[0], a0);
            a1 = fmaf(q4[1], v[1], a1);
            a2 = fmaf(q4[2], v[2], a2);
            a3 = fmaf(q4[3], v[3], a3);
        }
        s_base[w][h] = (a0 + a1) + (a2 + a3);
    }

    // ---- V B-fragments in registers ----
    bf16x8 bv[5][2];
    #pragma unroll
    for (int nt = 0; nt < 5; ++nt)
        #pragma unroll
        for (int ks = 0; ks < 2; ++ks) {
            int off = (nt * 16 + c16) * D_ + ks * 32 + g16 * 8;
            bf16x8 a8 = *(const bf16x8*)&wsA[off];
            bf16x8 c8 = *(const bf16x8*)&wsC[off];
            f32x4 q0 = *(const f32x4*)&s_q[w][ks * 32 + g16 * 8];
            f32x4 q1 = *(const f32x4*)&s_q[w][ks * 32 + g16 * 8 + 4];
            bf16x8 v8;
            v8[0] = (__bf16)((float)a8[0] + q0[0] * (float)c8[0]);
            v8[1] = (__bf16)((float)a8[1] + q0[1] * (float)c8[1]);
            v8[2] = (__bf16)((float)a8[2] + q0[2] * (float)c8[2]);
            v8[3] = (__bf16)((float)a8[3] + q0[3] * (float)c8[3]);
            v8[4] = (__bf16)((float)a8[4] + q1[0] * (float)c8[4]);
            v8[5] = (__bf16)((float)a8[5] + q1[1] * (float)c8[5]);
            v8[6] = (__bf16)((float)a8[6] + q1[2] * (float)c8[6]);
            v8[7] = (__bf16)((float)a8[7] + q1[3] * (float)c8[7]);
            bv[nt][ks] = v8;
        }

    // ---- zero h1 pad cols 80..95 for all 32 rows (once) ----
    {
        int row = lane & 31, c0 = 80 + (lane >> 5) * 8;
        *(uint4*)&s_h1[w][row * HSTR + c0] = make_uint4(0u, 0u, 0u, 0u);
    }

    float base_c[5];
    #pragma unroll
    for (int nt = 0; nt < 5; ++nt) base_c[nt] = s_base[w][nt * 16 + c16];
    __bf16* myh = &s_h1[w][0];

    // ---- flash state ----
    float o00,o01,o02,o03,o04,o05,o06,o07,o08,o09,o10,o11,o12,o13,o14,o15;
    o00=o01=o02=o03=o04=o05=o06=o07=o08=o09=o10=o11=o12=o13=o14=o15=0.0f;
    float m_run = -1e30f, l_run = 0.0f;

    // ---------------- main loop: 32 rows (two 16-row m-tiles) per iteration ----------------
    for (int pp = 0; pp < npairs; ++pp) {
        // convert current pair to bf16 frags (frees u for prefetch)
        bf16x8 afA0, afA1, afB0, afB1;
        afA0[0]=(__bf16)uA0.x; afA0[1]=(__bf16)uA0.y; afA0[2]=(__bf16)uA0.z; afA0[3]=(__bf16)uA0.w;
        afA0[4]=(__bf16)uA1.x; afA0[5]=(__bf16)uA1.y; afA0[6]=(__bf16)uA1.z; afA0[7]=(__bf16)uA1.w;
        afA1[0]=(__bf16)uA2.x; afA1[1]=(__bf16)uA2.y; afA1[2]=(__bf16)uA2.z; afA1[3]=(__bf16)uA2.w;
        afA1[4]=(__bf16)uA3.x; afA1[5]=(__bf16)uA3.y; afA1[6]=(__bf16)uA3.z; afA1[7]=(__bf16)uA3.w;
        afB0[0]=(__bf16)uB0.x; afB0[1]=(__bf16)uB0.y; afB0[2]=(__bf16)uB0.z; afB0[3]=(__bf16)uB0.w;
        afB0[4]=(__bf16)uB1.x; afB0[5]=(__bf16)uB1.y; afB0[6]=(__bf16)uB1.z; afB0[7]=(__bf16)uB1.w;
        afB1[0]=(__bf16)uB2.x; afB1[1]=(__bf16)uB2.y; afB1[2]=(__bf16)uB2.z; afB1[3]=(__bf16)uB2.w;
        afB1[4]=(__bf16)uB3.x; afB1[5]=(__bf16)uB3.y; afB1[6]=(__bf16)uB3.z; afB1[7]=(__bf16)uB3.w;

        // prefetch next pair
        if (pp + 1 < npairs) {
            int trA = (pp + 1) * 32 + c16;
            int trB = trA + 16;
            const float* krA = kb + (size_t)((trA < T_) ? trA : (T_ - 1)) * D_ + g16 * 8;
            const float* krB = kb + (size_t)((trB < T_) ? trB : (T_ - 1)) * D_ + g16 * 8;
            uA0 = *(const float4*)(krA);      uA1 = *(const float4*)(krA + 4);
            uA2 = *(const float4*)(krA + 32); uA3 = *(const float4*)(krA + 36);
            uB0 = *(const float4*)(krB);      uB1 = *(const float4*)(krB + 4);
            uB2 = *(const float4*)(krB + 32); uB3 = *(const float4*)(krB + 36);
        }

        // layer 1 (A then B) -> sigmoid -> h1 rows 0..15 / 16..31
        #pragma unroll
        for (int nt = 0; nt < 5; ++nt) {
            float bb = base_c[nt];
            f32x4 cA = { bb, bb, bb, bb };
            cA = __builtin_amdgcn_mfma_f32_16x16x32_bf16(afA0, bv[nt][0], cA, 0, 0, 0);
            cA = __builtin_amdgcn_mfma_f32_16x16x32_bf16(afA1, bv[nt][1], cA, 0, 0, 0);
            f32x4 cB = { bb, bb, bb, bb };
            cB = __builtin_amdgcn_mfma_f32_16x16x32_bf16(afB0, bv[nt][0], cB, 0, 0, 0);
            cB = __builtin_amdgcn_mfma_f32_16x16x32_bf16(afB1, bv[nt][1], cB, 0, 0, 0);
            #pragma unroll
            for (int r = 0; r < 4; ++r) {
                myh[(g16 * 4 + r) * HSTR + nt * 16 + c16]        = (__bf16)sigmoidf_(cA[r]);
                myh[(16 + g16 * 4 + r) * HSTR + nt * 16 + c16]   = (__bf16)sigmoidf_(cB[r]);
            }
        }

        // layer 2 (A and B)
        bf16x8 a2A0 = *(const bf16x8*)&myh[c16 * HSTR + g16 * 8];
        bf16x8 a2A1 = *(const bf16x8*)&myh[c16 * HSTR + 32 + g16 * 8];
        bf16x8 a2A2 = *(const bf16x8*)&myh[c16 * HSTR + 64 + g16 * 8];
        bf16x8 a2B0 = *(const bf16x8*)&myh[(16 + c16) * HSTR + g16 * 8];
        bf16x8 a2B1 = *(const bf16x8*)&myh[(16 + c16) * HSTR + 32 + g16 * 8];
        bf16x8 a2B2 = *(const bf16x8*)&myh[(16 + c16) * HSTR + 64 + g16 * 8];
        f32x4 acc2A[3], acc2B[3];
        #pragma unroll
        for (int nt = 0; nt < 3; ++nt) {
            float bb = b2c[nt];
            f32x4 cA = { bb, bb, bb, bb };
            cA = __builtin_amdgcn_mfma_f32_16x16x32_bf16(a2A0, bw[nt][0], cA, 0, 0, 0);
            cA = __builtin_amdgcn_mfma_f32_16x16x32_bf16(a2A1, bw[nt][1], cA, 0, 0, 0);
            cA = __builtin_amdgcn_mfma_f32_16x16x32_bf16(a2A2, bw[nt][2], cA, 0, 0, 0);
            acc2A[nt] = cA;
            f32x4 cB = { bb, bb, bb, bb };
            cB = __builtin_amdgcn_mfma_f32_16x16x32_bf16(a2B0, bw[nt][0], cB, 0, 0, 0);
            cB = __builtin_amdgcn_mfma_f32_16x16x32_bf16(a2B1, bw[nt][1], cB, 0, 0, 0);
            cB = __builtin_amdgcn_mfma_f32_16x16x32_bf16(a2B2, bw[nt][2], cB, 0, 0, 0);
            acc2B[nt] = cB;
        }

        // layer 3: 8 independent shfl-reduce chains -> masked scores
        const int tb = pp * 32;
        #pragma unroll
        for (int r = 0; r < 4; ++r) {
            float pA = sigmoidf_(acc2A[0][r]) * w3c[0]
                     + sigmoidf_(acc2A[1][r]) * w3c[1]
                     + sigmoidf_(acc2A[2][r]) * w3c[2];
            float pB = sigmoidf_(acc2B[0][r]) * w3c[0]
                     + sigmoidf_(acc2B[1][r]) * w3c[1]
                     + sigmoidf_(acc2B[2][r]) * w3c[2];
            pA += __shfl_xor(pA, 1);  pB += __shfl_xor(pB, 1);
            pA += __shfl_xor(pA, 2);  pB += __shfl_xor(pB, 2);
            pA += __shfl_xor(pA, 4);  pB += __shfl_xor(pB, 4);
            pA += __shfl_xor(pA, 8);  pB += __shfl_xor(pB, 8);
            if (c16 == 0) {
                int tA = tb + g16 * 4 + r;
                int tB = tA + 16;
                s_sc[w][g16 * 4 + r]      = (tA < mv) ? (pA + b3v) * 0.125f : -1e30f;
                s_sc[w][16 + g16 * 4 + r] = (tB < mv) ? (pB + b3v) * 0.125f : -1e30f;
            }
        }

        // online softmax for 32 rows (lane's rows: tb+c16 and tb+16+c16)
        float sA = s_sc[w][c16];
        float sB = s_sc[w][16 + c16];
        float tm = fmaxf(sA, sB);
        tm = fmaxf(tm, __shfl_xor(tm, 1));
        tm = fmaxf(tm, __shfl_xor(tm, 2));
        tm = fmaxf(tm, __shfl_xor(tm, 4));
        tm = fmaxf(tm, __shfl_xor(tm, 8));
        float m_new = fmaxf(m_run, tm);
        float alpha = __expf(m_run - m_new);
        float pA = __expf(sA - m_new);
        float pB = __expf(sB - m_new);
        float psum = pA + pB;
        psum += __shfl_xor(psum, 1);
        psum += __shfl_xor(psum, 2);
        psum += __shfl_xor(psum, 4);
        psum += __shfl_xor(psum, 8);
        l_run = l_run * alpha + psum;
        #define OUP(O, IA, IB) O = fmaf(pB, (float)(IB), fmaf(pA, (float)(IA), O * alpha));
        OUP(o00, afA0[0], afB0[0])  OUP(o01, afA0[1], afB0[1])
        OUP(o02, afA0[2], afB0[2])  OUP(o03, afA0[3], afB0[3])
        OUP(o04, afA0[4], afB0[4])  OUP(o05, afA0[5], afB0[5])
        OUP(o06, afA0[6], afB0[6])  OUP(o07, afA0[7], afB0[7])
        OUP(o08, afA1[0], afB1[0])  OUP(o09, afA1[1], afB1[1])
        OUP(o10, afA1[2], afB1[2])  OUP(o11, afA1[3], afB1[3])
        OUP(o12, afA1[4], afB1[4])  OUP(o13, afA1[5], afB1[5])
        OUP(o14, afA1[6], afB1[6])  OUP(o15, afA1[7], afB1[7])
        #undef OUP
        m_run = m_new;
    }

    // ---------------- finalize ----------------
    #define ORED(X) X += __shfl_xor(X,1); X += __shfl_xor(X,2); X += __shfl_xor(X,4); X += __shfl_xor(X,8);
    ORED(o00) ORED(o01) ORED(o02) ORED(o03) ORED(o04) ORED(o05) ORED(o06) ORED(o07)
    ORED(o08) ORED(o09) ORED(o10) ORED(o11) ORED(o12) ORED(o13) ORED(o14) ORED(o15)
    #undef ORED
    float inv_total = __builtin_amdgcn_rcpf(l_run);
    if (c16 == 0) {
        float* sp = &s_part[w][0];
        sp[g16 * 8 + 0] = o00;  sp[g16 * 8 + 1] = o01;
        sp[g16 * 8 + 2] = o02;  sp[g16 * 8 + 3] = o03;
        sp[g16 * 8 + 4] = o04;  sp[g16 * 8 + 5] = o05;
        sp[g16 * 8 + 6] = o06;  sp[g16 * 8 + 7] = o07;
        sp[32 + g16 * 8 + 0] = o08;  sp[32 + g16 * 8 + 1] = o09;
        sp[32 + g16 * 8 + 2] = o10;  sp[32 + g16 * 8 + 3] = o11;
        sp[32 + g16 * 8 + 4] = o12;  sp[32 + g16 * 8 + 5] = o13;
        sp[32 + g16 * 8 + 6] = o14;  sp[32 + g16 * 8 + 7] = o15;
    }
    asm volatile("s_waitcnt lgkmcnt(0)" ::: "memory");
    out[b * D_ + lane] = s_part[w][lane] * inv_total;
}

extern "C" void kernel_launch(void* const* d_in, const int* in_sizes, int n_in,
                              void* d_out, int out_size, void* d_ws, size_t ws_size,
                              hipStream_t stream)
{
    const float* query = (const float*)d_in[0];
    const float* key   = (const float*)d_in[1];
    const int*   mask  = (const int*)  d_in[2];
    const float* W1    = (const float*)d_in[3];
    const float* b1    = (const float*)d_in[4];
    const float* W2    = (const float*)d_in[5];
    const float* b2    = (const float*)d_in[6];
    const float* W3    = (const float*)d_in[7];
    const float* b3    = (const float*)d_in[8];
    float* out = (float*)d_out;

    prep_kernel<<<8, 256, 0, stream>>>(W1, W2, d_ws);
    attn_din11<<<512, 256, 0, stream>>>(query, key, mask, b1, b2, W3, b3, d_ws, out);
}